// Round 7
// baseline (883.365 us; speedup 1.0000x reference)
//
#include <hip/hip_runtime.h>
#include <stdint.h>

// ============================================================================
// LSTM (B=2048,T=256,D=32,H=256) + FC(256) on gfx950.
// R11 = R10 exchange + TWO batch-tiles per block (latency hidden by ILP).
// 128 blocks = 64 bt-pairs x 2 col-groups (pair k <-> k+64, same XCD),
// 512 thr (8 waves). Block (pairid,cg) owns batch tiles bt0=2*pairid,
// bt1=2*pairid+1 (32 rows) for hidden half cg; weights (144 VGPR/wave)
// shared by both tiles. R10 post-mortem: first tag-check always missed
// (post-to-check slack < coherence visibility ~500-1000cy) -> 1-2 retries
// x ~700cy every step. With 2 tiles the posts move to ~50%/~90% of the step
// and the checks to ~30%/~75% of the NEXT step -> slack 0.6-0.8P >= delta,
// first check hits, exchange leaves the critical path. Tiles run strictly
// sequentially (acc sets never coexist -> no VGPR blowup; R5's failure was
// flags+tid0+drains, all gone here). 3 lgkm-only barriers/step.
// Registers forbid real TLP: every wave carries 144 weight VGPRs -> 2
// waves/SIMD max (R7/R9 arithmetic), so ILP is the only latency-hiding left.
// Exchange (R10): slab dword = h_short | tag<<16; 16B dwordx4 sc0 sc1
// store/load; every dword self-validates (torn/stale -> retry, never
// accepted). Parity double-buffer + recurrence dep = WAR-safe.
// MFMA layouts (learn_hip verified): A[m=lane&15][k=(lane>>4)*8+j],
// B^T same, C/D: col=lane&15, row=(lane>>4)*4+reg.
// ============================================================================

typedef __attribute__((ext_vector_type(8))) short short8;
typedef __attribute__((ext_vector_type(4))) float f32x4;
typedef __attribute__((ext_vector_type(4))) uint32_t u32x4;
typedef unsigned long long ull;

#define LDSTRIDE 296  // 288 K-cols + 8 pad shorts
#define NBT 128       // batch tiles

// lgkm-only barrier: LDS visibility across waves WITHOUT draining VMEM.
#define BARRIER_LGKM() \
  asm volatile("s_waitcnt lgkmcnt(0)\n\ts_barrier" ::: "memory")

__device__ __forceinline__ short f2bf(float f) {
  uint32_t u = __builtin_bit_cast(uint32_t, f);
  u = (u + 0x7FFFu + ((u >> 16) & 1u)) >> 16;  // RNE
  return (short)(uint16_t)u;
}

#define LOG2E 1.4426950408889634f
__device__ __forceinline__ float sigmoidf_(float x) {
  return __builtin_amdgcn_rcpf(1.0f + __builtin_amdgcn_exp2f(-LOG2E * x));
}
__device__ __forceinline__ float tanhf_(float x) {
  float t = __builtin_amdgcn_exp2f((2.0f * LOG2E) * x);
  return 1.0f - 2.0f * __builtin_amdgcn_rcpf(t + 1.0f);
}

// 16B coherent load (bypass L1/L2 to the coherence point), wait inside.
__device__ __forceinline__ u32x4 load16_sc(const uint32_t* p) {
  u32x4 r;
  asm volatile("global_load_dwordx4 %0, %1, off sc0 sc1\n\ts_waitcnt vmcnt(0)"
               : "=v"(r)
               : "v"(p)
               : "memory");
  return r;
}
// 16B write-through store (non-atomic; dwords self-validate via tags).
__device__ __forceinline__ void store16_sc(uint32_t* p, u32x4 v) {
  asm volatile("global_store_dwordx4 %0, %1, off sc0 sc1" ::"v"(p), "v"(v)
               : "memory");
}

// zero the 4MB xchg buffer (tags must start != 1..256)
__global__ void zero_xchg(ull* __restrict__ x) {
  size_t i = ((size_t)blockIdx.x * 256 + threadIdx.x) * 4;
  x[i] = 0; x[i + 1] = 0; x[i + 2] = 0; x[i + 3] = 0;
}

// ---------------------------------------------------------------------------
// Pack W_hh[1024x256] (k 0..255) + W_ih[1024x32] (k 256..287) into bf16 frags.
// frag = ((kt*2 + cg)*8 + hu)*4 + g ; element (lane,j):
//   n = g*256 + cg*128 + hu*16 + (lane&15), k = kt*32 + (lane>>4)*8 + j
// ---------------------------------------------------------------------------
__global__ void pack_w(const float* __restrict__ Whh, const float* __restrict__ Wih,
                       short* __restrict__ wpack) {
  int tid = blockIdx.x * 256 + threadIdx.x;  // 576 frags * 64 lanes
  if (tid >= 576 * 64) return;
  int lane = tid & 63;
  int frag = tid >> 6;
  int g = frag & 3, hu = (frag >> 2) & 7, cg = (frag >> 5) & 1, kt = frag >> 6;
  int n = g * 256 + cg * 128 + hu * 16 + (lane & 15);
  int k0 = kt * 32 + (lane >> 4) * 8;
  short8 v;
#pragma unroll
  for (int j = 0; j < 8; ++j) {
    int k = k0 + j;
    float f = (k < 256) ? Whh[n * 256 + k] : Wih[n * 32 + (k - 256)];
    v[j] = f2bf(f);
  }
  *(short8*)(wpack + (size_t)frag * 512 + lane * 8) = v;
}

// W_fc[256x256] -> frags (kt 0..7, ct 0..15): n = ct*16+(lane&15).
__global__ void pack_wfc(const float* __restrict__ Wfc, short* __restrict__ wfc) {
  int tid = blockIdx.x * 256 + threadIdx.x;  // 128 frags * 64 lanes
  if (tid >= 128 * 64) return;
  int lane = tid & 63;
  int frag = tid >> 6;
  int ct = frag & 15, kt = frag >> 4;
  int n = ct * 16 + (lane & 15);
  int k0 = kt * 32 + (lane >> 4) * 8;
  short8 v;
#pragma unroll
  for (int j = 0; j < 8; ++j) v[j] = f2bf(Wfc[n * 256 + k0 + j]);
  *(short8*)(wfc + (size_t)frag * 512 + lane * 8) = v;
}

// slab dword index: [parity][bt][cg][tid] x 4 dwords (16B per thread)
#define SLABD(p, c, BT) \
  ((((((size_t)(p)) * NBT + (BT)) * 2 + (c)) * 512 + tid) * 4)

// ---------------------------------------------------------------------------
// Main kernel: grid 128; pairid = blockIdx&63, cg = blockIdx>>6 (same-XCD pair)
// ---------------------------------------------------------------------------
__global__ __launch_bounds__(512, 2) void lstm_main(
    const float* __restrict__ obs, const short8* __restrict__ wpack,
    const short8* __restrict__ wfc, const float* __restrict__ b_ih,
    const float* __restrict__ b_hh, const float* __restrict__ b_fc,
    uint32_t* __restrict__ xchg, float* __restrict__ out) {
  __shared__ __align__(16) short A[2][2][16 * LDSTRIDE];  // [tile][parity]
  const int tid = threadIdx.x;
  const int w = tid >> 6, lane = tid & 63;
  const int l15 = lane & 15, quad = lane >> 4;
  const int pairid = blockIdx.x & 63, cg = blockIdx.x >> 6;
  const int bt0 = pairid * 2, bt1 = bt0 + 1;
  const int row0 = bt0 * 16, row1 = bt1 * 16;
  const int xr = tid >> 5, xd = tid & 31;  // x staging: row, d
  const int kro = (cg ^ 1) * 4;            // remote ktile base
  const int klo = cg * 4;                  // local ktile base

  // zero all A buffers (h_0 = 0)
  {
    short* Az = &A[0][0][0];
    for (int i = tid; i < 2 * 2 * 16 * LDSTRIDE; i += 512) Az[i] = 0;
  }

  // persistent weight registers: 36 frags, SHARED by both tiles (same cg)
  short8 wfr[9][4];
#pragma unroll
  for (int kt = 0; kt < 9; ++kt)
#pragma unroll
    for (int g = 0; g < 4; ++g)
      wfr[kt][g] = wpack[(size_t)(((kt * 2 + cg) * 8 + w) * 4 + g) * 64 + lane];
#pragma unroll
  for (int kt = 0; kt < 9; ++kt)
#pragma unroll
    for (int g = 0; g < 4; ++g)
      asm volatile("" : "+v"(wfr[kt][g]));  // R9 pin (anti-remat insurance)

  // fused bias per gate for this lane's hidden unit (col = cg*128+w*16+l15)
  float bias[4];
#pragma unroll
  for (int g = 0; g < 4; ++g) {
    int idx = g * 256 + cg * 128 + w * 16 + l15;
    bias[g] = b_ih[idx] + b_hh[idx];
  }

  float c0s[4], c1s[4];
#pragma unroll
  for (int i = 0; i < 4; ++i) { c0s[i] = 0.f; c1s[i] = 0.f; }

  __syncthreads();  // zeroing done (cold path: full barrier fine)
  A[0][0][xr * LDSTRIDE + 256 + xd] =
      f2bf(obs[((size_t)(row0 + xr) * 256 + 0) * 32 + xd]);
  A[1][0][xr * LDSTRIDE + 256 + xd] =
      f2bf(obs[((size_t)(row1 + xr) * 256 + 0) * 32 + xd]);
  __syncthreads();  // x_0 staged

// 4 MFMAs (all gates) for one compile-time ktile (wfr index must be constant)
#define MFK(KT)                                                                \
  {                                                                            \
    const short8 a_ =                                                          \
        *(const short8*)&Acur[l15 * LDSTRIDE + (KT)*32 + quad * 8];            \
    acc[0] = __builtin_amdgcn_mfma_f32_16x16x32_bf16(a_, wfr[KT][0], acc[0],   \
                                                     0, 0, 0);                 \
    acc[1] = __builtin_amdgcn_mfma_f32_16x16x32_bf16(a_, wfr[KT][1], acc[1],   \
                                                     0, 0, 0);                 \
    acc[2] = __builtin_amdgcn_mfma_f32_16x16x32_bf16(a_, wfr[KT][2], acc[2],   \
                                                     0, 0, 0);                 \
    acc[3] = __builtin_amdgcn_mfma_f32_16x16x32_bf16(a_, wfr[KT][3], acc[3],   \
                                                     0, 0, 0);                 \
  }

  for (int t = 0; t < 256; ++t) {
    const int p = t & 1;
    short* __restrict__ A0c = &A[0][p][0];
    short* __restrict__ A0n = &A[0][p ^ 1][0];
    short* __restrict__ A1c = &A[1][p][0];
    short* __restrict__ A1n = &A[1][p ^ 1][0];
    const int tn = (t < 255) ? (t + 1) : 255;

    // speculative sibling loads for BOTH tiles (issue order fixed: sv0, sv1)
    const uint32_t* sa0 = xchg + SLABD(p, cg ^ 1, bt0);
    const uint32_t* sa1 = xchg + SLABD(p, cg ^ 1, bt1);
    u32x4 sv0 = (u32x4){0, 0, 0, 0}, sv1 = (u32x4){0, 0, 0, 0};
    if (t > 0) {
      asm volatile("global_load_dwordx4 %0, %1, off sc0 sc1"
                   : "=v"(sv0) : "v"(sa0) : "memory");
      asm volatile("global_load_dwordx4 %0, %1, off sc0 sc1"
                   : "=v"(sv1) : "v"(sa1) : "memory");
    }
    // obs prefetch (pinned after the spec loads by the asm memory clobbers;
    // register-carried across the barriers to phase-x)
    const float xv0 = obs[((size_t)(row0 + xr) * 256 + tn) * 32 + xd];
    const float xv1 = obs[((size_t)(row1 + xr) * 256 + tn) * 32 + xd];

    // ========================= tile 0 =========================
    {
      short* __restrict__ Acur = A0c;
      f32x4 acc[4];
#pragma unroll
      for (int g = 0; g < 4; ++g)
        acc[g] = (f32x4){bias[g], bias[g], bias[g], bias[g]};
      if (cg == 0) { MFK(0) MFK(1) MFK(2) MFK(3) }
      else         { MFK(4) MFK(5) MFK(6) MFK(7) }
      MFK(8)  // x ktile

      if (t > 0) {
        // queue: {sv0, sv1, xv0, xv1} -> vmcnt(3) retires exactly sv0
        asm volatile("s_waitcnt vmcnt(3)" : "+v"(sv0)::"memory");
        __builtin_amdgcn_sched_barrier(0);
        const uint32_t want = (uint32_t)t << 16;
        for (;;) {
          const uint32_t bad =
              ((sv0[0] ^ want) | (sv0[1] ^ want) | (sv0[2] ^ want) |
               (sv0[3] ^ want)) & 0xFFFF0000u;
          if (!bad) break;
          __builtin_amdgcn_s_sleep(2);
          sv0 = load16_sc(sa0);
        }
        const int scol = kro * 32 + w * 16 + l15;
        A0c[(quad * 4 + 0) * LDSTRIDE + scol] = (short)(uint16_t)sv0[0];
        A0c[(quad * 4 + 1) * LDSTRIDE + scol] = (short)(uint16_t)sv0[1];
        A0c[(quad * 4 + 2) * LDSTRIDE + scol] = (short)(uint16_t)sv0[2];
        A0c[(quad * 4 + 3) * LDSTRIDE + scol] = (short)(uint16_t)sv0[3];
      }
      BARRIER_LGKM();  // BAR-A: T0 sib-half visible

      if (cg == 0) { MFK(4) MFK(5) MFK(6) MFK(7) }
      else         { MFK(0) MFK(1) MFK(2) MFK(3) }

      short hb[4];
#pragma unroll
      for (int reg = 0; reg < 4; ++reg) {
        float iv = sigmoidf_(acc[0][reg]);
        float fv = sigmoidf_(acc[1][reg]);
        float gv = tanhf_(acc[2][reg]);
        float ov = sigmoidf_(acc[3][reg]);
        float cc = fv * c0s[reg] + iv * gv;
        c0s[reg] = cc;
        hb[reg] = f2bf(ov * tanhf_(cc));
      }
      {  // post T0 (~50% through step) then own-h LDS write
        const uint32_t tg1 = (uint32_t)(t + 1) << 16;
        u32x4 pv = (u32x4){tg1 | (uint16_t)hb[0], tg1 | (uint16_t)hb[1],
                           tg1 | (uint16_t)hb[2], tg1 | (uint16_t)hb[3]};
        store16_sc(xchg + SLABD((t + 1) & 1, cg, bt0), pv);
      }
      {
        const int ocol = klo * 32 + w * 16 + l15;
#pragma unroll
        for (int reg = 0; reg < 4; ++reg)
          A0n[(quad * 4 + reg) * LDSTRIDE + ocol] = hb[reg];
      }
    }

    // ========================= tile 1 =========================
    {
      short* __restrict__ Acur = A1c;
      f32x4 acc[4];
#pragma unroll
      for (int g = 0; g < 4; ++g)
        acc[g] = (f32x4){bias[g], bias[g], bias[g], bias[g]};
      if (cg == 0) { MFK(0) MFK(1) MFK(2) MFK(3) }
      else         { MFK(4) MFK(5) MFK(6) MFK(7) }
      MFK(8)  // x ktile

      if (t > 0) {
        // queue (oldest->newest): [sv1?, xv0?, xv1?, post0] -> vmcnt(1)
        // retires sv1 (and obs) but NEVER waits on the post0 store.
        asm volatile("s_waitcnt vmcnt(1)" : "+v"(sv1)::"memory");
        __builtin_amdgcn_sched_barrier(0);
        const uint32_t want = (uint32_t)t << 16;
        for (;;) {
          const uint32_t bad =
              ((sv1[0] ^ want) | (sv1[1] ^ want) | (sv1[2] ^ want) |
               (sv1[3] ^ want)) & 0xFFFF0000u;
          if (!bad) break;
          __builtin_amdgcn_s_sleep(2);
          sv1 = load16_sc(sa1);
        }
        const int scol = kro * 32 + w * 16 + l15;
        A1c[(quad * 4 + 0) * LDSTRIDE + scol] = (short)(uint16_t)sv1[0];
        A1c[(quad * 4 + 1) * LDSTRIDE + scol] = (short)(uint16_t)sv1[1];
        A1c[(quad * 4 + 2) * LDSTRIDE + scol] = (short)(uint16_t)sv1[2];
        A1c[(quad * 4 + 3) * LDSTRIDE + scol] = (short)(uint16_t)sv1[3];
      }
      BARRIER_LGKM();  // BAR-B: T1 sib-half + T0 own-h visible

      if (cg == 0) { MFK(4) MFK(5) MFK(6) MFK(7) }
      else         { MFK(0) MFK(1) MFK(2) MFK(3) }

      short hb[4];
#pragma unroll
      for (int reg = 0; reg < 4; ++reg) {
        float iv = sigmoidf_(acc[0][reg]);
        float fv = sigmoidf_(acc[1][reg]);
        float gv = tanhf_(acc[2][reg]);
        float ov = sigmoidf_(acc[3][reg]);
        float cc = fv * c1s[reg] + iv * gv;
        c1s[reg] = cc;
        hb[reg] = f2bf(ov * tanhf_(cc));
      }
      {  // post T1 (~90% through step)
        const uint32_t tg1 = (uint32_t)(t + 1) << 16;
        u32x4 pv = (u32x4){tg1 | (uint16_t)hb[0], tg1 | (uint16_t)hb[1],
                           tg1 | (uint16_t)hb[2], tg1 | (uint16_t)hb[3]};
        store16_sc(xchg + SLABD((t + 1) & 1, cg, bt1), pv);
      }
      {
        const int ocol = klo * 32 + w * 16 + l15;
#pragma unroll
        for (int reg = 0; reg < 4; ++reg)
          A1n[(quad * 4 + reg) * LDSTRIDE + ocol] = hb[reg];
      }
    }

    // x_{t+1} into both next-parity buffers
    A0n[xr * LDSTRIDE + 256 + xd] = f2bf(xv0);
    A1n[xr * LDSTRIDE + 256 + xd] = f2bf(xv1);
    BARRIER_LGKM();  // BAR-C: end of step
  }
#undef MFK

  // ---- final exchange: complete h_256 (parity 0, tag 256) for the FC ----
#pragma unroll
  for (int ti = 0; ti < 2; ++ti) {
    const uint32_t* sa = xchg + SLABD(0, cg ^ 1, (ti ? bt1 : bt0));
    const uint32_t want = 256u << 16;
    u32x4 sv = load16_sc(sa);
    for (;;) {
      const uint32_t bad = ((sv[0] ^ want) | (sv[1] ^ want) | (sv[2] ^ want) |
                            (sv[3] ^ want)) & 0xFFFF0000u;
      if (!bad) break;
      __builtin_amdgcn_s_sleep(2);
      sv = load16_sc(sa);
    }
    const int scol = kro * 32 + w * 16 + l15;
    short* Af = &A[ti][0][0];
    Af[(quad * 4 + 0) * LDSTRIDE + scol] = (short)(uint16_t)sv[0];
    Af[(quad * 4 + 1) * LDSTRIDE + scol] = (short)(uint16_t)sv[1];
    Af[(quad * 4 + 2) * LDSTRIDE + scol] = (short)(uint16_t)sv[2];
    Af[(quad * 4 + 3) * LDSTRIDE + scol] = (short)(uint16_t)sv[3];
  }
  __syncthreads();  // cold path: full barrier fine

  // FC epilogue: wave w -> cols (cg*8+w)*16..+16, rows of both tiles
  {
    const int ct = cg * 8 + w;
    const int col = ct * 16 + l15;
    const float bv = b_fc[col];
#pragma unroll
    for (int ti = 0; ti < 2; ++ti) {
      const short* Af = &A[ti][0][0];
      f32x4 ao = (f32x4){0.f, 0.f, 0.f, 0.f};
#pragma unroll
      for (int kt = 0; kt < 8; ++kt) {
        const short8 a = *(const short8*)&Af[l15 * LDSTRIDE + kt * 32 + quad * 8];
        const short8 b = wfc[(size_t)(kt * 16 + ct) * 64 + lane];
        ao = __builtin_amdgcn_mfma_f32_16x16x32_bf16(a, b, ao, 0, 0, 0);
      }
      const int rbase = (ti ? row1 : row0) + quad * 4;
#pragma unroll
      for (int reg = 0; reg < 4; ++reg)
        out[(size_t)(rbase + reg) * 256 + col] = ao[reg] + bv;
    }
  }
}

extern "C" void kernel_launch(void* const* d_in, const int* in_sizes, int n_in,
                              void* d_out, int out_size, void* d_ws, size_t ws_size,
                              hipStream_t stream) {
  const float* obs  = (const float*)d_in[0];   // [2048,256,32]
  const float* W_ih = (const float*)d_in[1];   // [1024,32]
  const float* W_hh = (const float*)d_in[2];   // [1024,256]
  const float* b_ih = (const float*)d_in[3];   // [1024]
  const float* b_hh = (const float*)d_in[4];   // [1024]
  const float* W_fc = (const float*)d_in[5];   // [256,256]
  const float* b_fc = (const float*)d_in[6];   // [256]
  float* out = (float*)d_out;                  // [2048,256]

  // ws layout
  short*    wpack = (short*)d_ws;                      // 576*512 shorts = 576 KB
  short*    wfcp  = wpack + 576 * 512;                 // 128*512 shorts = 128 KB
  uint32_t* xchg  = (uint32_t*)((char*)d_ws + (576 + 128) * 1024);  // 4 MB slabs

  hipLaunchKernelGGL(zero_xchg, dim3(512), dim3(256), 0, stream, (ull*)xchg);
  hipLaunchKernelGGL(pack_w, dim3(144), dim3(256), 0, stream, W_hh, W_ih, wpack);
  hipLaunchKernelGGL(pack_wfc, dim3(32), dim3(256), 0, stream, W_fc, wfcp);
  hipLaunchKernelGGL(lstm_main, dim3(128), dim3(512), 0, stream, obs,
                     (const short8*)wpack, (const short8*)wfcp,
                     b_ih, b_hh, b_fc, xchg, out);
}

// Round 9
// 738.140 us; speedup vs baseline: 1.1967x; 1.1967x over previous
//
#include <hip/hip_runtime.h>
#include <stdint.h>

// ============================================================================
// LSTM (B=2048,T=256,D=32,H=256) + FC(256) on gfx950.
// R13 = R10 structure + DEVICE-scope exchange via PROVEN-VISIBLE primitives.
// R12 ("sc1"-only plain stores) never returned a result (container failed
// twice) -- possible GPU hang: non-atomic sc1 stores are cache-policy hints
// and may sit dirty in the producer XCD's L2 while sc1 polls are serviced at
// the IC -> infinite spin. R6 proved {HIP agent atomic store -> HIP agent
// atomic load} is eventually-visible on this chip; R10 proved the wide
// self-validating format + speculation + backoff. R13 composes exactly those:
//  - producer: 2x 8B __hip_atomic_store relaxed AGENT (executes at device
//    coherence point; cannot be stranded in L2; cannot hang)
//  - consumer: speculative 16B asm load (sc1; stale data harmless -- every
//    dword self-validates) checked after local GEMM; retries use 2x 8B
//    __hip_atomic_load relaxed AGENT with s_sleep(2) backoff.
//  - format: dword = h_short | tag<<16 (R10), so 16B spec load and 8B atomic
//    ops interoperate; 8B store atomicity covers both dwords trivially.
// Scope theory under test: R10's sc0sc1 (system scope) ops round-trip past
// the IC (~2-3k cy visibility -> 3-4 retries/step = the 3300cy residual);
// device scope should cut delta to ~500-800cy -> first check hits or 1 retry.
// Structure (R10, unchanged): 256 blocks = 128 batch-tiles x 2 col-groups
// (pair b <-> b+128, same XCD), 512 thr (8 waves), 1 block/CU. Wave w owns
// hidden units cg*128+w*16..+16, all 4 gates; 36 weight frags pinned
// resident. GEMM split local (own h-half + x) / remote (sibling half).
// Parity double-buffer + recurrence dependence = WAR-safe. lgkm-only
// barriers in the hot loop (vmcnt stays in flight across barriers).
// MFMA layouts (learn_hip verified): A[m=lane&15][k=(lane>>4)*8+j],
// B^T same, C/D: col=lane&15, row=(lane>>4)*4+reg.
// ============================================================================

typedef __attribute__((ext_vector_type(8))) short short8;
typedef __attribute__((ext_vector_type(4))) float f32x4;
typedef __attribute__((ext_vector_type(4))) uint32_t u32x4;
typedef unsigned long long ull;

#define LDSTRIDE 296  // 288 K-cols + 8 pad shorts
#define NBT 128       // batch tiles

// lgkm-only barrier: LDS visibility across waves WITHOUT draining VMEM.
#define BARRIER_LGKM() \
  asm volatile("s_waitcnt lgkmcnt(0)\n\ts_barrier" ::: "memory")

__device__ __forceinline__ short f2bf(float f) {
  uint32_t u = __builtin_bit_cast(uint32_t, f);
  u = (u + 0x7FFFu + ((u >> 16) & 1u)) >> 16;  // RNE
  return (short)(uint16_t)u;
}

#define LOG2E 1.4426950408889634f
__device__ __forceinline__ float sigmoidf_(float x) {
  return __builtin_amdgcn_rcpf(1.0f + __builtin_amdgcn_exp2f(-LOG2E * x));
}
__device__ __forceinline__ float tanhf_(float x) {
  float t = __builtin_amdgcn_exp2f((2.0f * LOG2E) * x);
  return 1.0f - 2.0f * __builtin_amdgcn_rcpf(t + 1.0f);
}

// zero the 4MB xchg buffer (tags must start != 1..256)
__global__ void zero_xchg(ull* __restrict__ x) {
  size_t i = ((size_t)blockIdx.x * 256 + threadIdx.x) * 4;
  x[i] = 0; x[i + 1] = 0; x[i + 2] = 0; x[i + 3] = 0;
}

// ---------------------------------------------------------------------------
// Pack W_hh[1024x256] (k 0..255) + W_ih[1024x32] (k 256..287) into bf16 frags.
// frag = ((kt*2 + cg)*8 + hu)*4 + g ; element (lane,j):
//   n = g*256 + cg*128 + hu*16 + (lane&15), k = kt*32 + (lane>>4)*8 + j
// ---------------------------------------------------------------------------
__global__ void pack_w(const float* __restrict__ Whh, const float* __restrict__ Wih,
                       short* __restrict__ wpack) {
  int tid = blockIdx.x * 256 + threadIdx.x;  // 576 frags * 64 lanes
  if (tid >= 576 * 64) return;
  int lane = tid & 63;
  int frag = tid >> 6;
  int g = frag & 3, hu = (frag >> 2) & 7, cg = (frag >> 5) & 1, kt = frag >> 6;
  int n = g * 256 + cg * 128 + hu * 16 + (lane & 15);
  int k0 = kt * 32 + (lane >> 4) * 8;
  short8 v;
#pragma unroll
  for (int j = 0; j < 8; ++j) {
    int k = k0 + j;
    float f = (k < 256) ? Whh[n * 256 + k] : Wih[n * 32 + (k - 256)];
    v[j] = f2bf(f);
  }
  *(short8*)(wpack + (size_t)frag * 512 + lane * 8) = v;
}

// W_fc[256x256] -> frags (kt 0..7, ct 0..15): n = ct*16+(lane&15).
__global__ void pack_wfc(const float* __restrict__ Wfc, short* __restrict__ wfc) {
  int tid = blockIdx.x * 256 + threadIdx.x;  // 128 frags * 64 lanes
  if (tid >= 128 * 64) return;
  int lane = tid & 63;
  int frag = tid >> 6;
  int ct = frag & 15, kt = frag >> 4;
  int n = ct * 16 + (lane & 15);
  int k0 = kt * 32 + (lane >> 4) * 8;
  short8 v;
#pragma unroll
  for (int j = 0; j < 8; ++j) v[j] = f2bf(Wfc[n * 256 + k0 + j]);
  *(short8*)(wfc + (size_t)frag * 512 + lane * 8) = v;
}

// slab dword index: [parity][bt][cg][tid] x 4 dwords (16B per thread)
#define SLABD(p, c) (((((size_t)(p)) * NBT + bt) * 2 + (c)) * 512 + tid) * 4

// ---------------------------------------------------------------------------
// Main kernel: grid 256; bt = blockIdx&127, cg = blockIdx>>7 (same-XCD pair).
// ---------------------------------------------------------------------------
__global__ __launch_bounds__(512, 2) void lstm_main(
    const float* __restrict__ obs, const short8* __restrict__ wpack,
    const short8* __restrict__ wfc, const float* __restrict__ b_ih,
    const float* __restrict__ b_hh, const float* __restrict__ b_fc,
    uint32_t* __restrict__ xchg, float* __restrict__ out) {
  __shared__ __align__(16) short A[2][16 * LDSTRIDE];  // parity double-buffer
  const int tid = threadIdx.x;
  const int w = tid >> 6, lane = tid & 63;
  const int l15 = lane & 15, quad = lane >> 4;
  const int bt = blockIdx.x & 127, cg = blockIdx.x >> 7;
  const int row0 = bt * 16;
  const int xr = tid >> 5, xd = tid & 31;  // x staging: row, d
  const int kro = (cg ^ 1) * 4;            // remote ktile base
  const int klo = cg * 4;                  // local ktile base

  // zero both A buffers (h_0 = 0)
  {
    short* Az = &A[0][0];
    for (int i = tid; i < 2 * 16 * LDSTRIDE; i += 512) Az[i] = 0;
  }

  // persistent weight registers: 36 frags (live in the unified RF)
  short8 wfr[9][4];
#pragma unroll
  for (int kt = 0; kt < 9; ++kt)
#pragma unroll
    for (int g = 0; g < 4; ++g)
      wfr[kt][g] = wpack[(size_t)(((kt * 2 + cg) * 8 + w) * 4 + g) * 64 + lane];
#pragma unroll
  for (int kt = 0; kt < 9; ++kt)
#pragma unroll
    for (int g = 0; g < 4; ++g)
      asm volatile("" : "+v"(wfr[kt][g]));  // R9 pin (anti-remat insurance)

  // fused bias per gate for this lane's hidden unit (col = cg*128+w*16+l15)
  float bias[4];
#pragma unroll
  for (int g = 0; g < 4; ++g) {
    int idx = g * 256 + cg * 128 + w * 16 + l15;
    bias[g] = b_ih[idx] + b_hh[idx];
  }

  float c4[4];
#pragma unroll
  for (int i = 0; i < 4; ++i) c4[i] = 0.f;

  __syncthreads();  // zeroing done (cold path: full barrier fine)
  A[0][xr * LDSTRIDE + 256 + xd] =
      f2bf(obs[((size_t)(row0 + xr) * 256 + 0) * 32 + xd]);
  __syncthreads();  // x_0 staged

// 4 MFMAs (all gates) for one compile-time ktile (wfr index must be constant)
#define MFK(KT)                                                                \
  {                                                                            \
    const short8 a_ =                                                          \
        *(const short8*)&Acur[l15 * LDSTRIDE + (KT)*32 + quad * 8];            \
    acc[0] = __builtin_amdgcn_mfma_f32_16x16x32_bf16(a_, wfr[KT][0], acc[0],   \
                                                     0, 0, 0);                 \
    acc[1] = __builtin_amdgcn_mfma_f32_16x16x32_bf16(a_, wfr[KT][1], acc[1],   \
                                                     0, 0, 0);                 \
    acc[2] = __builtin_amdgcn_mfma_f32_16x16x32_bf16(a_, wfr[KT][2], acc[2],   \
                                                     0, 0, 0);                 \
    acc[3] = __builtin_amdgcn_mfma_f32_16x16x32_bf16(a_, wfr[KT][3], acc[3],   \
                                                     0, 0, 0);                 \
  }

  for (int t = 0; t < 256; ++t) {
    const int p = t & 1;
    short* __restrict__ Acur = &A[p][0];
    short* __restrict__ Anx = &A[p ^ 1][0];
    const int tn = (t < 255) ? (t + 1) : 255;

    // early-issue speculative sibling slab load (16B, sc1 policy; stale data
    // is harmless -- every dword self-validates and the retry path below uses
    // proven-visible agent atomics). Latency overlaps the local GEMM.
    const uint32_t* sa = xchg + SLABD(p, cg ^ 1);
    const ull* sa8 = (const ull*)sa;
    u32x4 sv = (u32x4){0, 0, 0, 0};
    if (t > 0)
      asm volatile("global_load_dwordx4 %0, %1, off sc1"
                   : "=v"(sv)
                   : "v"(sa)
                   : "memory");

    // obs prefetch x_{t+1} (consumed at phase 6; stays in flight)
    const float xv = obs[((size_t)(row0 + xr) * 256 + tn) * 32 + xd];

    // phase 1: LOCAL GEMM (own h-half + x) -- needs nothing from sibling
    f32x4 acc[4];
#pragma unroll
    for (int g = 0; g < 4; ++g)
      acc[g] = (f32x4){bias[g], bias[g], bias[g], bias[g]};
    if (cg == 0) { MFK(0) MFK(1) MFK(2) MFK(3) }
    else         { MFK(4) MFK(5) MFK(6) MFK(7) }
    MFK(8)  // x ktile

    // phase 2: validate tags / backoff-poll, scatter into Acur sib-half
    if (t > 0) {
      // wait for the speculative load only (obs prefetch stays outstanding);
      // "+v"(sv) ties the wait to the data so uses cannot be hoisted (rule 18)
      asm volatile("s_waitcnt vmcnt(1)" : "+v"(sv)::"memory");
      __builtin_amdgcn_sched_barrier(0);
      const uint32_t want = (uint32_t)t << 16;
      for (;;) {
        const uint32_t bad = ((sv[0] ^ want) | (sv[1] ^ want) | (sv[2] ^ want) |
                              (sv[3] ^ want)) & 0xFFFF0000u;
        if (!bad) break;
        __builtin_amdgcn_s_sleep(2);  // ~128cy backoff: no poll storm
        // retry via PROVEN-VISIBLE device-scope atomic loads (R6 semantics)
        const ull a0 = __hip_atomic_load(&sa8[0], __ATOMIC_RELAXED,
                                         __HIP_MEMORY_SCOPE_AGENT);
        const ull a1 = __hip_atomic_load(&sa8[1], __ATOMIC_RELAXED,
                                         __HIP_MEMORY_SCOPE_AGENT);
        sv[0] = (uint32_t)a0;
        sv[1] = (uint32_t)(a0 >> 32);
        sv[2] = (uint32_t)a1;
        sv[3] = (uint32_t)(a1 >> 32);
      }
      const int scol = kro * 32 + w * 16 + l15;
      Acur[(quad * 4 + 0) * LDSTRIDE + scol] = (short)(uint16_t)sv[0];
      Acur[(quad * 4 + 1) * LDSTRIDE + scol] = (short)(uint16_t)sv[1];
      Acur[(quad * 4 + 2) * LDSTRIDE + scol] = (short)(uint16_t)sv[2];
      Acur[(quad * 4 + 3) * LDSTRIDE + scol] = (short)(uint16_t)sv[3];
    }
    // phase 3: sib-half visible to all waves (LDS-only visibility)
    BARRIER_LGKM();

    // phase 4: REMOTE GEMM (sibling h-half)
    if (cg == 0) { MFK(4) MFK(5) MFK(6) MFK(7) }
    else         { MFK(0) MFK(1) MFK(2) MFK(3) }

    // phase 5: gates
    short hb[4];
#pragma unroll
    for (int reg = 0; reg < 4; ++reg) {
      float iv = sigmoidf_(acc[0][reg]);
      float fv = sigmoidf_(acc[1][reg]);
      float gv = tanhf_(acc[2][reg]);
      float ov = sigmoidf_(acc[3][reg]);
      float cc = fv * c4[reg] + iv * gv;
      c4[reg] = cc;
      hb[reg] = f2bf(ov * tanhf_(cc));
    }

    // phase 6: tagged slab store -- 2x 8B DEVICE-scope atomics (executes at
    // the device coherence point; cannot be stranded in L2; cannot hang) --
    // then LDS writes for the local halves.
    {
      const uint32_t tg1 = (uint32_t)(t + 1) << 16;
      ull* ds8 = (ull*)(xchg + SLABD((t + 1) & 1, cg));
      const ull w0 = ((ull)(tg1 | (uint16_t)hb[1]) << 32) |
                     (ull)(tg1 | (uint16_t)hb[0]);
      const ull w1 = ((ull)(tg1 | (uint16_t)hb[3]) << 32) |
                     (ull)(tg1 | (uint16_t)hb[2]);
      __hip_atomic_store(&ds8[0], w0, __ATOMIC_RELAXED,
                         __HIP_MEMORY_SCOPE_AGENT);
      __hip_atomic_store(&ds8[1], w1, __ATOMIC_RELAXED,
                         __HIP_MEMORY_SCOPE_AGENT);
    }
    {
      const int ocol = klo * 32 + w * 16 + l15;
#pragma unroll
      for (int reg = 0; reg < 4; ++reg)
        Anx[(quad * 4 + reg) * LDSTRIDE + ocol] = hb[reg];
      Anx[xr * LDSTRIDE + 256 + xd] = f2bf(xv);
    }
    // phase 7: own-half h_{t+1} + x_{t+1} visible (LDS-only; the slab store
    // acks must NOT gate the next step)
    BARRIER_LGKM();
  }
#undef MFK

  // ---- final exchange: complete h_256 (parity 0, tag 256) for the FC ----
  {
    const ull* sa8 = (const ull*)(xchg + SLABD(0, cg ^ 1));
    const uint32_t want = 256u << 16;
    u32x4 sv;
    for (;;) {
      const ull a0 = __hip_atomic_load(&sa8[0], __ATOMIC_RELAXED,
                                       __HIP_MEMORY_SCOPE_AGENT);
      const ull a1 = __hip_atomic_load(&sa8[1], __ATOMIC_RELAXED,
                                       __HIP_MEMORY_SCOPE_AGENT);
      sv[0] = (uint32_t)a0;
      sv[1] = (uint32_t)(a0 >> 32);
      sv[2] = (uint32_t)a1;
      sv[3] = (uint32_t)(a1 >> 32);
      const uint32_t bad = ((sv[0] ^ want) | (sv[1] ^ want) | (sv[2] ^ want) |
                            (sv[3] ^ want)) & 0xFFFF0000u;
      if (!bad) break;
      __builtin_amdgcn_s_sleep(2);
    }
    const int scol = kro * 32 + w * 16 + l15;
    A[0][(quad * 4 + 0) * LDSTRIDE + scol] = (short)(uint16_t)sv[0];
    A[0][(quad * 4 + 1) * LDSTRIDE + scol] = (short)(uint16_t)sv[1];
    A[0][(quad * 4 + 2) * LDSTRIDE + scol] = (short)(uint16_t)sv[2];
    A[0][(quad * 4 + 3) * LDSTRIDE + scol] = (short)(uint16_t)sv[3];
  }
  __syncthreads();  // cold path: full barrier fine

  // FC epilogue: wave w -> out rows bt*16..+16, cols (cg*8+w)*16..+16
  {
    const int ct = cg * 8 + w;
    const int col = ct * 16 + l15;
    const float bv = b_fc[col];
    f32x4 ao = (f32x4){0.f, 0.f, 0.f, 0.f};
#pragma unroll
    for (int kt = 0; kt < 8; ++kt) {
      const short8 a = *(const short8*)&A[0][l15 * LDSTRIDE + kt * 32 + quad * 8];
      const short8 b = wfc[(size_t)(kt * 16 + ct) * 64 + lane];
      ao = __builtin_amdgcn_mfma_f32_16x16x32_bf16(a, b, ao, 0, 0, 0);
    }
#pragma unroll
    for (int reg = 0; reg < 4; ++reg) {
      const int row = row0 + quad * 4 + reg;
      out[(size_t)row * 256 + col] = ao[reg] + bv;
    }
  }
}

extern "C" void kernel_launch(void* const* d_in, const int* in_sizes, int n_in,
                              void* d_out, int out_size, void* d_ws, size_t ws_size,
                              hipStream_t stream) {
  const float* obs  = (const float*)d_in[0];   // [2048,256,32]
  const float* W_ih = (const float*)d_in[1];   // [1024,32]
  const float* W_hh = (const float*)d_in[2];   // [1024,256]
  const float* b_ih = (const float*)d_in[3];   // [1024]
  const float* b_hh = (const float*)d_in[4];   // [1024]
  const float* W_fc = (const float*)d_in[5];   // [256,256]
  const float* b_fc = (const float*)d_in[6];   // [256]
  float* out = (float*)d_out;                  // [2048,256]

  // ws layout
  short*    wpack = (short*)d_ws;                      // 576*512 shorts = 576 KB
  short*    wfcp  = wpack + 576 * 512;                 // 128*512 shorts = 128 KB
  uint32_t* xchg  = (uint32_t*)((char*)d_ws + (576 + 128) * 1024);  // 4 MB slabs

  hipLaunchKernelGGL(zero_xchg, dim3(512), dim3(256), 0, stream, (ull*)xchg);
  hipLaunchKernelGGL(pack_w, dim3(144), dim3(256), 0, stream, W_hh, W_ih, wpack);
  hipLaunchKernelGGL(pack_wfc, dim3(32), dim3(256), 0, stream, W_fc, wfcp);
  hipLaunchKernelGGL(lstm_main, dim3(256), dim3(512), 0, stream, obs,
                     (const short8*)wpack, (const short8*)wfcp,
                     b_ih, b_hh, b_fc, xchg, out);
}